// Round 8
// baseline (568.658 us; speedup 1.0000x reference)
//
#include <hip/hip_runtime.h>
#include <hip/hip_bf16.h>
#include <math.h>

// ---------------------------------------------------------------------------
// TransformerDecoderBlock  (B=4, S=2048, E=768, DFF=3072)
// Round 8: R7 tiled-operand layout with the vtb batch-offset fix.
//   Every GEMM input stored as 128x32 tiles (4096 elems: [kg][row][8]).
//   Staging = contiguous 8KB copy (coalesced global_load_lds); fragment
//   ds_read_b128 conflict-free. R7 bug: mode-2 epilogue used the 4-batch
//   total (6291456) as the per-batch vtb stride; correct is N*2048
//   (=1572864), matching the PV consumer's b*S*E indexing.
// ---------------------------------------------------------------------------

typedef __bf16 bf16_t;
typedef bf16_t bf16x8 __attribute__((ext_vector_type(8)));
typedef float f32x4 __attribute__((ext_vector_type(4)));

#define TBM 128
#define TBN 128
#define CPAD 136  // epilogue staging stride

struct MMDesc {
    const bf16_t* A;   // tiled
    const bf16_t* B;   // tiled
    const float* bias;
    __hip_bfloat16* C;
    float* lsum;
    int koff;
    int mode;  // 0=row-major C (ldc=N), 1=tiled C, 2=trans-tiled (vtb)
};
struct MMArgs { MMDesc g[8]; };

// async global->LDS, 16B per lane. LDS dest = wave-uniform base + lane*16.
__device__ __forceinline__ void load16(const bf16_t* g, bf16_t* l) {
    __builtin_amdgcn_global_load_lds(
        (const __attribute__((address_space(1))) unsigned int*)g,
        (__attribute__((address_space(3))) unsigned int*)l, 16, 0, 0);
}

// K-loop core. At/Bt point at tile-row base; k-tile kt at +kt*4096.
// Two 32-K slabs per barrier pair; K multiple of 64.
__device__ __forceinline__ void mm_core(
    const bf16_t* At, const bf16_t* Bt, int K,
    bf16_t* Asm, bf16_t* Bsm, int w, int l, int wm, int wn, f32x4 acc[4][4]) {
    const int go = w * 1024 + l * 8;  // lane offset within 2-tile pair
    const int lo = w * 1024;          // wave-uniform LDS base
    const int fr = l & 15;
    const int kg = (l >> 4) * 1024;

    for (int k0 = 0; k0 < K; k0 += 64) {
        const bf16_t* a = At + (long)(k0 >> 5) * 4096;
        const bf16_t* b = Bt + (long)(k0 >> 5) * 4096;
        load16(a + go, Asm + lo);
        load16(a + go + 512, Asm + lo + 512);
        load16(b + go, Bsm + lo);
        load16(b + go + 512, Bsm + lo + 512);
        load16(a + go + 4096, Asm + lo + 4096);
        load16(a + go + 4608, Asm + lo + 4608);
        load16(b + go + 4096, Bsm + lo + 4096);
        load16(b + go + 4608, Bsm + lo + 4608);
        __syncthreads();

#pragma unroll
        for (int t = 0; t < 2; ++t) {
            const bf16_t* As = Asm + t * 4096;
            const bf16_t* Bs = Bsm + t * 4096;
            bf16x8 af[4], bfr[4];
#pragma unroll
            for (int i = 0; i < 4; ++i)
                af[i] = *(const bf16x8*)(As + kg + (wm + i * 16 + fr) * 8);
#pragma unroll
            for (int j = 0; j < 4; ++j)
                bfr[j] = *(const bf16x8*)(Bs + kg + (wn + j * 16 + fr) * 8);
#pragma unroll
            for (int i = 0; i < 4; ++i)
#pragma unroll
                for (int j = 0; j < 4; ++j)
                    acc[i][j] = __builtin_amdgcn_mfma_f32_16x16x32_bf16(
                        af[i], bfr[j], acc[i][j], 0, 0, 0);
        }
        __syncthreads();
    }
}

// copy-out from LDS staging ct (stride CPAD) to destination.
__device__ __forceinline__ void tile_out_row(
    const __hip_bfloat16* ct, __hip_bfloat16* base, int N, int tid) {
#pragma unroll
    for (int u = 0; u < 8; ++u) {
        const int e = u * 2048 + tid * 8;
        const int rl = e >> 7, cl = e & 127;
        *(uint4*)(base + (long)rl * N + cl) = *(const uint4*)(ct + rl * CPAD + cl);
    }
}
__device__ __forceinline__ void tile_out_tiled(
    const __hip_bfloat16* ct, __hip_bfloat16* tb, int tid) {
#pragma unroll
    for (int u = 0; u < 8; ++u) {
        const int idx = u * 256 + tid;
        const int r = idx & 127, sk = idx >> 7;
        *(uint4*)(tb + (long)sk * 1024 + r * 8) = *(const uint4*)(ct + r * CPAD + sk * 8);
    }
}

// Standard GEMM: C = scale*A@B^T + bias, opt ReLU, bf16 out.
// CLAMPK: K clamped to (by+1)*TBM - koff (causal PV); zero tile if <=0.
template <bool RELU, bool CLAMPK>
__global__ __launch_bounds__(256) void mm_std(
    MMArgs args, int N, int K, int ldtA, int ldtB, float scale, int GX) {
    __shared__ __align__(16) bf16_t smem[128 * CPAD];  // 34816 B (union)
    bf16_t* Asm = smem;
    bf16_t* Bsm = smem + 8192;

    const MMDesc dsc = args.g[blockIdx.z];

    // panel swizzle: 8 consecutive blocks share one B-tile
    const int lin = blockIdx.x;
    const int panel = lin / (8 * GX);
    const int rem = lin - panel * 8 * GX;
    const int bx = rem >> 3;
    const int by = panel * 8 + (rem & 7);

    const int m0 = by * TBM, n0 = bx * TBN;
    const int tid = threadIdx.x, w = tid >> 6, l = tid & 63;
    const int wm = (w >> 1) * 64, wn = (w & 1) * 64;
    const int fr = l & 15;

    f32x4 acc[4][4];
    const f32x4 z4 = {0.f, 0.f, 0.f, 0.f};
#pragma unroll
    for (int i = 0; i < 4; ++i)
#pragma unroll
        for (int j = 0; j < 4; ++j) acc[i][j] = z4;

    int Keff = K;
    if (CLAMPK) {
        int km = (by + 1) * TBM - dsc.koff;
        Keff = km < K ? km : K;
    }
    if (!CLAMPK || Keff > 0)
        mm_core(dsc.A + (long)(m0 >> 7) * ldtA * 4096,
                dsc.B + (long)(n0 >> 7) * ldtB * 4096,
                Keff, Asm, Bsm, w, l, wm, wn, acc);

    // epilogue: bias/scale/relu in-register -> LDS stage -> coalesced out
    __hip_bfloat16* ct = (__hip_bfloat16*)smem;
    const int erow = (l >> 4) * 4;
#pragma unroll
    for (int j = 0; j < 4; ++j) {
        const int cl = wn + j * 16 + fr;
        const float bv = dsc.bias ? dsc.bias[n0 + cl] : 0.f;
#pragma unroll
        for (int i = 0; i < 4; ++i) {
            const int rl = wm + i * 16 + erow;
#pragma unroll
            for (int r = 0; r < 4; ++r) {
                float v = acc[i][j][r] * scale + bv;
                if (RELU) v = fmaxf(v, 0.f);
                const int idx = (dsc.mode == 2) ? (cl * CPAD + rl + r)
                                                : ((rl + r) * CPAD + cl);
                ct[idx] = __float2bfloat16(v);
            }
        }
    }
    __syncthreads();
    if (dsc.mode == 0) {
        tile_out_row(ct, dsc.C + (long)m0 * N + n0, N, tid);
    } else if (dsc.mode == 1) {
        tile_out_tiled(ct, dsc.C + ((long)(m0 >> 7) * (N >> 5) + (n0 >> 5)) * 4096, tid);
    } else {
        // trans -> vtb[batch][N rows][2048 cols] tiled (ldt=64).
        // per-batch stride = N*2048 (R7 bug: used 4-batch total 6291456).
        __hip_bfloat16* tb = dsc.C + (long)(m0 >> 11) * N * 2048 +
                             ((long)(n0 >> 7) * 64 + ((m0 & 2047) >> 5)) * 4096;
        tile_out_tiled(ct, tb, tid);
    }
}

// QK^T with fused exp epilogue: P~ = exp(scale*(A@B^T)) written bf16 tiled,
// per-row sums atomically added to lsum. CAUSAL: lower-triangle tiles only.
template <bool CAUSAL>
__global__ __launch_bounds__(256) void mm_exp(
    MMArgs args, int N, int K, int ldtA, int ldtB, float scale, int GX) {
    __shared__ __align__(16) bf16_t smem[128 * CPAD];
    bf16_t* Asm = smem;
    bf16_t* Bsm = smem + 8192;

    const MMDesc dsc = args.g[blockIdx.z];

    int bx, by;
    if (CAUSAL) {
        const int t = blockIdx.x;
        by = (int)((sqrtf(8.f * t + 1.f) - 1.f) * 0.5f);
        while ((by + 1) * (by + 2) / 2 <= t) ++by;
        while (by * (by + 1) / 2 > t) --by;
        bx = t - by * (by + 1) / 2;
    } else {
        const int lin = blockIdx.x;
        const int panel = lin / (8 * GX);
        const int rem = lin - panel * 8 * GX;
        bx = rem >> 3;
        by = panel * 8 + (rem & 7);
    }

    const int m0 = by * TBM, n0 = bx * TBN;
    const int tid = threadIdx.x, w = tid >> 6, l = tid & 63;
    const int wm = (w >> 1) * 64, wn = (w & 1) * 64;
    const int fr = l & 15;

    f32x4 acc[4][4];
    const f32x4 z4 = {0.f, 0.f, 0.f, 0.f};
#pragma unroll
    for (int i = 0; i < 4; ++i)
#pragma unroll
        for (int j = 0; j < 4; ++j) acc[i][j] = z4;

    mm_core(dsc.A + (long)(m0 >> 7) * ldtA * 4096,
            dsc.B + (long)(n0 >> 7) * ldtB * 4096,
            K, Asm, Bsm, w, l, wm, wn, acc);

    __hip_bfloat16* ct = (__hip_bfloat16*)smem;
    const int erow = (l >> 4) * 4;
#pragma unroll
    for (int i = 0; i < 4; ++i) {
#pragma unroll
        for (int r = 0; r < 4; ++r) {
            const int rl = wm + i * 16 + erow + r;
            const int grow = m0 + rl;
            float rs = 0.f;
#pragma unroll
            for (int j = 0; j < 4; ++j) {
                const int cl = wn + j * 16 + fr;
                float e;
                if (CAUSAL && (n0 + cl) > grow)
                    e = 0.f;
                else
                    e = __expf(acc[i][j][r] * scale);
                ct[rl * CPAD + cl] = __float2bfloat16(e);
                rs += e;
            }
#pragma unroll
            for (int o = 8; o > 0; o >>= 1) rs += __shfl_down(rs, o, 16);
            if ((l & 15) == 0) atomicAdd(&dsc.lsum[grow], rs);
        }
    }
    __syncthreads();
    tile_out_tiled(ct, dsc.C + ((long)(m0 >> 7) * (N >> 5) + (n0 >> 5)) * 4096, tid);
}

// ---------------- reductions ----------------
__device__ __forceinline__ float waveReduceSum(float v) {
#pragma unroll
    for (int o = 32; o > 0; o >>= 1) v += __shfl_down(v, o, 64);
    return v;
}
__device__ __forceinline__ float blockReduceSum(float v, float* s) {
    int lane = threadIdx.x & 63, w = threadIdx.x >> 6;
    v = waveReduceSum(v);
    __syncthreads();
    if (lane == 0) s[w] = v;
    __syncthreads();
    return s[0] + s[1] + s[2] + s[3];
}

// tiled bf16 index for a [rows][768] activation buffer (24 tiles per row)
__device__ __forceinline__ long tidx768(long row, int c) {
    return ((row >> 7) * 24 + (c >> 5)) * 4096 + ((c & 31) >> 3) * 1024 +
           (row & 127) * 8 + (c & 7);
}

// out = LayerNorm(xbase + t) * g + beta.  h1,h2 bf16 row-major partials.
// t = (h1+h2)/lsum[row] (attention) or relu(h1+h2+hbias) (BR, MLP2).
// XF32: residual from fp32 xf (row-major), else bf16 xh (tiled).
// outb (tiled) and/or outf (row-major fp32). In-place outb==xh ok.
template <bool BR, bool XF32>
__global__ __launch_bounds__(256) void ln_kernel(
    const float* __restrict__ xf, const __hip_bfloat16* __restrict__ xh,
    const __hip_bfloat16* __restrict__ h1, const __hip_bfloat16* __restrict__ h2,
    const float* __restrict__ hbias, const float* __restrict__ lsum,
    const float* __restrict__ g, const float* __restrict__ beta,
    float* __restrict__ outf, __hip_bfloat16* __restrict__ outb) {
    __shared__ float red[4];
    const int E = 768;
    const long row = blockIdx.x;
    const float hscale = lsum ? (1.f / lsum[row]) : 1.f;

    float vals[3];
    float sum = 0.f;
#pragma unroll
    for (int i = 0; i < 3; ++i) {
        int c = threadIdx.x + i * 256;
        float t = __bfloat162float(h1[row * E + c]) + __bfloat162float(h2[row * E + c]);
        if (BR) t = fmaxf(t + hbias[c], 0.f);
        else t *= hscale;
        float xv = XF32 ? xf[row * E + c] : __bfloat162float(xh[tidx768(row, c)]);
        vals[i] = xv + t;
        sum += vals[i];
    }
    sum = blockReduceSum(sum, red);
    const float mean = sum * (1.f / 768.f);

    float ss = 0.f;
#pragma unroll
    for (int i = 0; i < 3; ++i) {
        float d = vals[i] - mean;
        ss += d * d;
    }
    ss = blockReduceSum(ss, red);
    const float inv = rsqrtf(ss * (1.f / 768.f) + 1e-5f);

#pragma unroll
    for (int i = 0; i < 3; ++i) {
        int c = threadIdx.x + i * 256;
        float v = (vals[i] - mean) * inv * g[c] + beta[c];
        if (outf) outf[row * E + c] = v;
        if (outb) outb[tidx768(row, c)] = __float2bfloat16(v);
    }
}

// fp32 -> bf16 tiled conversion; one block per 128x32 tile.
struct CvtArgs {
    const float* s[10];
    __hip_bfloat16* d[10];
    int cols[10];
    int start[11];
};
__global__ __launch_bounds__(256) void cvt_all(CvtArgs a) {
    const int t = blockIdx.x;
    int i = 0;
    while (t >= a.start[i + 1]) ++i;
    const int local = t - a.start[i];
    const int C = a.cols[i];
    const int tpr = C >> 5;
    const int tr = local / tpr, tc = local - tr * tpr;
    const float* src = a.s[i] + (long)tr * 128 * C + tc * 32;
    __hip_bfloat16* dst = a.d[i] + (long)local * 4096;

#pragma unroll
    for (int it = 0; it < 2; ++it) {
        const int u = threadIdx.x + it * 256;  // 0..511
        const int r = u >> 2, kgp = u & 3;
        const float* sp = src + (long)r * C + kgp * 8;
        float4 v0 = *(const float4*)sp;
        float4 v1 = *(const float4*)(sp + 4);
        union { __hip_bfloat16 h[8]; uint4 q; } tmp;
        tmp.h[0] = __float2bfloat16(v0.x);
        tmp.h[1] = __float2bfloat16(v0.y);
        tmp.h[2] = __float2bfloat16(v0.z);
        tmp.h[3] = __float2bfloat16(v0.w);
        tmp.h[4] = __float2bfloat16(v1.x);
        tmp.h[5] = __float2bfloat16(v1.y);
        tmp.h[6] = __float2bfloat16(v1.z);
        tmp.h[7] = __float2bfloat16(v1.w);
        *(uint4*)(dst + kgp * 1024 + r * 8) = tmp.q;
    }
}

extern "C" void kernel_launch(void* const* d_in, const int* in_sizes, int n_in,
                              void* d_out, int out_size, void* d_ws, size_t ws_size,
                              hipStream_t stream) {
    const int Bb = 4, S = 2048, E = 768, DFF = 3072;
    const int Nr = Bb * S;  // 8192

    const float* x    = (const float*)d_in[0];
    const float* kv   = (const float*)d_in[1];
    const float* wq_w = (const float*)d_in[2];
    const float* wq_b = (const float*)d_in[3];
    const float* wk_w = (const float*)d_in[4];
    const float* wk_b = (const float*)d_in[5];
    const float* wv_w = (const float*)d_in[6];
    const float* wv_b = (const float*)d_in[7];
    const float* ln1g = (const float*)d_in[8];
    const float* ln1b = (const float*)d_in[9];
    const float* wq2w = (const float*)d_in[10];
    const float* wq2b = (const float*)d_in[11];
    const float* wk2w = (const float*)d_in[12];
    const float* wk2b = (const float*)d_in[13];
    const float* wv2w = (const float*)d_in[14];
    const float* wv2b = (const float*)d_in[15];
    const float* ln2g = (const float*)d_in[16];
    const float* ln2b = (const float*)d_in[17];
    const float* w1   = (const float*)d_in[18];
    const float* b1   = (const float*)d_in[19];
    const float* w2   = (const float*)d_in[20];
    const float* b2   = (const float*)d_in[21];
    const float* ln3g = (const float*)d_in[22];
    const float* ln3b = (const float*)d_in[23];
    float* out = (float*)d_out;

    // ---- workspace (bump allocator, 256B aligned) ~155 MB ----
    char* wsp = (char*)d_ws;
    auto alloc = [&](size_t bytes) {
        char* p = wsp;
        wsp += (bytes + 255) & ~(size_t)255;
        return p;
    };
    const size_t nSE = (size_t)Nr * E;       // 6,291,456
    const size_t nSS = (size_t)Bb * S * S;   // 16,777,216
    __hip_bfloat16* Pb   = (__hip_bfloat16*)alloc(nSS * 2);   // tiled, 33.5 MB
    __hip_bfloat16* qb   = (__hip_bfloat16*)alloc(nSE * 2);   // tiled
    __hip_bfloat16* kb   = (__hip_bfloat16*)alloc(nSE * 2);   // tiled
    __hip_bfloat16* hffb = Pb;  // MLP hidden (tiled) overlays Pb+qb+kb
    __hip_bfloat16* vtb  = (__hip_bfloat16*)alloc(nSE * 2);   // V^T tiled, ldt 64
    __hip_bfloat16* xb   = (__hip_bfloat16*)alloc(nSE * 2);   // tiled
    __hip_bfloat16* kvb  = (__hip_bfloat16*)alloc(nSE * 2);   // tiled
    __hip_bfloat16* actb = (__hip_bfloat16*)alloc(nSE * 2);   // tiled residual
    __hip_bfloat16* hA   = (__hip_bfloat16*)alloc(nSE * 2);   // row-major partial
    __hip_bfloat16* hB   = (__hip_bfloat16*)alloc(nSE * 2);   // row-major partial
    __hip_bfloat16* wqb   = (__hip_bfloat16*)alloc((size_t)E * E * 2);
    __hip_bfloat16* wkb   = (__hip_bfloat16*)alloc((size_t)E * E * 2);
    __hip_bfloat16* wvb   = (__hip_bfloat16*)alloc((size_t)E * E * 2);
    __hip_bfloat16* wq2bm = (__hip_bfloat16*)alloc((size_t)E * E * 2);
    __hip_bfloat16* wk2bm = (__hip_bfloat16*)alloc((size_t)E * E * 2);
    __hip_bfloat16* wv2bm = (__hip_bfloat16*)alloc((size_t)E * E * 2);
    __hip_bfloat16* w1b   = (__hip_bfloat16*)alloc((size_t)DFF * E * 2);
    __hip_bfloat16* w2b   = (__hip_bfloat16*)alloc((size_t)E * DFF * 2);
    float* lsum1 = (float*)alloc((size_t)Nr * 4);
    float* lsum2 = (float*)alloc((size_t)Nr * 4);

    const float scale = 1.0f / sqrtf((float)E);
    const dim3 blk(256);

    hipMemsetAsync(lsum1, 0, (size_t)Nr * 4 * 2, stream);  // lsum1+lsum2

    // ---- all conversions (tiled) in one launch ----
    CvtArgs ca;
    const float* srcs[10] = {wq_w, wk_w, wv_w, wq2w, wk2w, wv2w, w1, w2, x, kv};
    __hip_bfloat16* dsts[10] = {wqb, wkb, wvb, wq2bm, wk2bm, wv2bm, w1b, w2b, xb, kvb};
    int colv[10] = {768, 768, 768, 768, 768, 768, 768, 3072, 768, 768};
    int tiles[10] = {144, 144, 144, 144, 144, 144, 576, 576, 1536, 1536};
    int acc0 = 0;
    for (int i = 0; i < 10; ++i) {
        ca.s[i] = srcs[i];
        ca.d[i] = dsts[i];
        ca.cols[i] = colv[i];
        ca.start[i] = acc0;
        acc0 += tiles[i];
    }
    ca.start[10] = acc0;  // 5088
    cvt_all<<<acc0, blk, 0, stream>>>(ca);

    // ---- causal self-attention ----
    {   // fused QKV projection; V written trans-tiled into vtb
        MMArgs a{};
        a.g[0] = {(const bf16_t*)xb, (const bf16_t*)wqb, wq_b, qb, nullptr, 0, 1};
        a.g[1] = {(const bf16_t*)xb, (const bf16_t*)wkb, wk_b, kb, nullptr, 0, 1};
        a.g[2] = {(const bf16_t*)xb, (const bf16_t*)wvb, wv_b, vtb, nullptr, 0, 2};
        mm_std<false, false><<<dim3(6 * 64, 1, 3), blk, 0, stream>>>(
            a, E, E, 24, 24, 1.f, 6);
    }
    {   // causal QK^T + exp: 136 triangle tiles x 4 batches
        MMArgs a{};
        for (int b = 0; b < 4; ++b)
            a.g[b] = {(const bf16_t*)qb + (long)b * S * E,
                      (const bf16_t*)kb + (long)b * S * E, nullptr,
                      Pb + (long)b * S * S, lsum1 + b * S, 0, 1};
        mm_exp<true><<<dim3(136, 1, 4), blk, 0, stream>>>(a, S, E, 24, 24, scale, 16);
    }
    {   // causal PV split-K=2 with K-clamp, row-major bf16 partials
        MMArgs a{};
        for (int b = 0; b < 4; ++b)
            for (int ks = 0; ks < 2; ++ks)
                a.g[b * 2 + ks] = {(const bf16_t*)Pb + (long)b * S * S + ks * 32 * 4096,
                                   (const bf16_t*)vtb + (long)b * S * E + ks * 32 * 4096,
                                   nullptr, (ks ? hB : hA) + (long)b * S * E,
                                   nullptr, ks * 1024, 0};
        mm_std<false, true><<<dim3(6 * 16, 1, 8), blk, 0, stream>>>(
            a, E, 1024, 64, 64, 1.f, 6);
    }
    ln_kernel<false, true><<<Nr, blk, 0, stream>>>(
        x, nullptr, hA, hB, nullptr, lsum1, ln1g, ln1b, nullptr, actb);

    // ---- cross-attention ----
    {   // grouped Q2(x1) + K2,V2(kv); V2 trans-tiled
        MMArgs a{};
        a.g[0] = {(const bf16_t*)actb, (const bf16_t*)wq2bm, wq2b, qb, nullptr, 0, 1};
        a.g[1] = {(const bf16_t*)kvb, (const bf16_t*)wk2bm, wk2b, kb, nullptr, 0, 1};
        a.g[2] = {(const bf16_t*)kvb, (const bf16_t*)wv2bm, wv2b, vtb, nullptr, 0, 2};
        mm_std<false, false><<<dim3(6 * 64, 1, 3), blk, 0, stream>>>(
            a, E, E, 24, 24, 1.f, 6);
    }
    {   // full QK^T + exp: 256 tiles x 4 batches
        MMArgs a{};
        for (int b = 0; b < 4; ++b)
            a.g[b] = {(const bf16_t*)qb + (long)b * S * E,
                      (const bf16_t*)kb + (long)b * S * E, nullptr,
                      Pb + (long)b * S * S, lsum2 + b * S, 0, 1};
        mm_exp<false><<<dim3(16 * 16, 1, 4), blk, 0, stream>>>(a, S, E, 24, 24, scale, 16);
    }
    {   // full PV split-K=2, row-major bf16 partials
        MMArgs a{};
        for (int b = 0; b < 4; ++b)
            for (int ks = 0; ks < 2; ++ks)
                a.g[b * 2 + ks] = {(const bf16_t*)Pb + (long)b * S * S + ks * 32 * 4096,
                                   (const bf16_t*)vtb + (long)b * S * E + ks * 32 * 4096,
                                   nullptr, (ks ? hB : hA) + (long)b * S * E,
                                   nullptr, 0, 0};
        mm_std<false, false><<<dim3(6 * 16, 1, 8), blk, 0, stream>>>(
            a, E, 1024, 64, 64, 1.f, 6);
    }
    ln_kernel<false, false><<<Nr, blk, 0, stream>>>(
        nullptr, actb, hA, hB, nullptr, lsum2, ln2g, ln2b, nullptr, actb);

    // ---- MLP ----
    {   // MLP1: 1536 blocks, fused bias+ReLU, tiled out (hffb overlays)
        MMArgs a{};
        a.g[0] = {(const bf16_t*)actb, (const bf16_t*)w1b, b1, hffb, nullptr, 0, 1};
        mm_std<true, false><<<dim3(24 * 64, 1, 1), blk, 0, stream>>>(
            a, DFF, E, 24, 24, 1.f, 24);
    }
    {   // MLP2 split-K=2, row-major partials; bias+ReLU in ln3
        MMArgs a{};
        a.g[0] = {(const bf16_t*)hffb, (const bf16_t*)w2b, nullptr, hA, nullptr, 0, 0};
        a.g[1] = {(const bf16_t*)hffb + 48 * 4096, (const bf16_t*)w2b + 48 * 4096,
                  nullptr, hB, nullptr, 0, 0};
        mm_std<false, false><<<dim3(6 * 64, 1, 2), blk, 0, stream>>>(
            a, E, 1536, 96, 96, 1.f, 6);
    }
    ln_kernel<true, false><<<Nr, blk, 0, stream>>>(
        nullptr, actb, hA, hB, b2, nullptr, ln3g, ln3b, out, nullptr);
}